// Round 3
// 626.526 us; speedup vs baseline: 1.0536x; 1.0536x over previous
//
#include <hip/hip_runtime.h>
#include <stdint.h>
#include <math.h>

#define SEQ   2048
#define DIM   4096
#define NHEAD 32
#define NKV   8
#define HD    128
#define KVDIM (NKV*HD)   // 1024

typedef __bf16 bf16x8 __attribute__((ext_vector_type(8)));
typedef float  f32x4  __attribute__((ext_vector_type(4)));

__device__ __forceinline__ uint16_t f2bf(float f) {
  uint32_t u = __float_as_uint(f);
  uint32_t r = (u + 0x7FFFu + ((u >> 16) & 1u)) >> 16;
  return (uint16_t)r;
}
__device__ __forceinline__ bf16x8 ld_frag(const uint16_t* p) {
  return *(const bf16x8*)p;
}
__device__ __forceinline__ void async_cp16(const void* g, void* lds) {
  __builtin_amdgcn_global_load_lds(
      (const __attribute__((address_space(1))) void*)g,
      (__attribute__((address_space(3))) void*)lds, 16, 0, 0);
}

// ---------------- fused fp32 -> bf16 conversion: x, wq, wk, wv ----------------
__global__ __launch_bounds__(256) void k_conv_all(
    const float* __restrict__ x, const float* __restrict__ wq,
    const float* __restrict__ wk, const float* __restrict__ wv,
    uint16_t* __restrict__ xb, uint16_t* __restrict__ wqkvb) {
  size_t i = (size_t)blockIdx.x * 256 + threadIdx.x;   // float4 index, 8M total
  const float* s; uint16_t* d; size_t off;
  if (i < 2097152)      { s = x;  d = xb;                 off = i; }
  else if (i < 6291456) { s = wq; d = wqkvb;              off = i - 2097152; }
  else if (i < 7340032) { s = wk; d = wqkvb + 16777216u;  off = i - 6291456; }
  else                  { s = wv; d = wqkvb + 20971520u;  off = i - 7340032; }
  const float4 v = ((const float4*)s)[off];
  ushort4 o;
  o.x = f2bf(v.x); o.y = f2bf(v.y); o.z = f2bf(v.z); o.w = f2bf(v.w);
  ((ushort4*)d)[off] = o;
}

__global__ __launch_bounds__(256) void k_conv(const float* __restrict__ s,
                                              uint16_t* __restrict__ d, int n4) {
  int i = blockIdx.x * 256 + threadIdx.x;
  if (i >= n4) return;
  const float4 v = ((const float4*)s)[i];
  ushort4 o;
  o.x = f2bf(v.x); o.y = f2bf(v.y); o.z = f2bf(v.z); o.w = f2bf(v.w);
  ((ushort4*)d)[i] = o;
}

// ======================================================================
// 256x256 NT GEMM core, BK=32, 8 waves (2Mx4N), 4-deep LDS tile ring,
// counted vmcnt (never drains in steady state), setprio around MFMA.
// LDS: 4 bufs x (256x32 A + 256x32 B) bf16 = 128 KiB.
// Swizzle: 16B chunk slot s of row r holds global chunk s ^ ((r>>1)&3)
// (pre-swizzled global source for global_load_lds + matching ds_read).
// ======================================================================
#define G256_TB   8192          /* elements per tile buffer (256*32) */

#define G256_PROLOGUE(Aptr, Bptr)                                               \
  __shared__ __align__(16) uint16_t sA[4 * G256_TB];                            \
  __shared__ __align__(16) uint16_t sB[4 * G256_TB];                            \
  const int tid  = threadIdx.x;                                                 \
  const int lane = tid & 63;                                                    \
  const int wv   = tid >> 6;                                                    \
  const int quad = lane >> 4;                                                   \
  const int l16  = lane & 15;                                                   \
  const int wm   = (wv >> 2) << 7;   /* 0 or 128 */                             \
  const int wn   = (wv & 3) << 6;    /* 0,64,128,192 */                         \
  const uint16_t* gA = Aptr + (size_t)m0 * DIM;                                 \
  const uint16_t* gB = Bptr + (size_t)n0 * DIM;                                 \
  const int srow0 = tid >> 2;                                                   \
  const int sc0   = (tid & 3) ^ ((srow0 >> 1) & 3);                             \
  const int srow1 = (512 + tid) >> 2;                                           \
  const int sc1   = (tid & 3) ^ ((srow1 >> 1) & 3);                             \
  const size_t sga0 = (size_t)srow0 * DIM + sc0 * 8;                            \
  const size_t sga1 = (size_t)srow1 * DIM + sc1 * 8;                            \
  int offA[8], offB[4];                                                         \
  _Pragma("unroll")                                                             \
  for (int t = 0; t < 8; t++) {                                                 \
    int r_ = wm + t * 16 + l16;                                                 \
    offA[t] = r_ * 32 + (quad ^ ((r_ >> 1) & 3)) * 8;                           \
  }                                                                             \
  _Pragma("unroll")                                                             \
  for (int t = 0; t < 4; t++) {                                                 \
    int r_ = wn + t * 16 + l16;                                                 \
    offB[t] = r_ * 32 + (quad ^ ((r_ >> 1) & 3)) * 8;                           \
  }                                                                             \
  f32x4 acc[8][4] = {};                                                         \
  /* prologue: stage tiles 0 and 1 */                                           \
  async_cp16(gA + sga0,      sA + tid * 8);                                     \
  async_cp16(gB + sga0,      sB + tid * 8);                                     \
  async_cp16(gA + sga1,      sA + 4096 + tid * 8);                              \
  async_cp16(gB + sga1,      sB + 4096 + tid * 8);                              \
  async_cp16(gA + sga0 + 32, sA + G256_TB + tid * 8);                           \
  async_cp16(gB + sga0 + 32, sB + G256_TB + tid * 8);                           \
  async_cp16(gA + sga1 + 32, sA + G256_TB + 4096 + tid * 8);                    \
  async_cp16(gB + sga1 + 32, sB + G256_TB + 4096 + tid * 8);                    \
  asm volatile("s_waitcnt vmcnt(4)" ::: "memory");  /* tile0 landed */          \
  __builtin_amdgcn_s_barrier();                                                 \
  for (int T = 0; T < 128; T++) {                                               \
    const int cb = (T & 3) * G256_TB;                                           \
    const uint16_t* bA = sA + cb;                                               \
    const uint16_t* bB = sB + cb;                                               \
    const int  k2 = (T + 2) * 32;                                               \
    const bool pf = (T + 2 < 128);                                              \
    const int  db = ((T + 2) & 3) * G256_TB;                                    \
    /* phase 0: read A rows 0-63 of wave + all B; stage half of T+2 */          \
    bf16x8 af0[4], bfv[4];                                                      \
    _Pragma("unroll")                                                           \
    for (int t = 0; t < 4; t++) {                                               \
      af0[t] = ld_frag(bA + offA[t]);                                           \
      bfv[t] = ld_frag(bB + offB[t]);                                           \
    }                                                                           \
    if (pf) {                                                                   \
      async_cp16(gA + sga0 + k2, sA + db + tid * 8);                            \
      async_cp16(gB + sga0 + k2, sB + db + tid * 8);                            \
    }                                                                           \
    __builtin_amdgcn_s_barrier();                                               \
    asm volatile("s_waitcnt lgkmcnt(0)" ::: "memory");                          \
    __builtin_amdgcn_sched_barrier(0);                                          \
    __builtin_amdgcn_s_setprio(1);                                              \
    _Pragma("unroll")                                                           \
    for (int mt = 0; mt < 4; mt++)                                              \
      _Pragma("unroll")                                                         \
      for (int nt = 0; nt < 4; nt++)                                            \
        acc[mt][nt] = __builtin_amdgcn_mfma_f32_16x16x32_bf16(af0[mt], bfv[nt], \
                                                              acc[mt][nt], 0, 0, 0); \
    __builtin_amdgcn_s_setprio(0);                                              \
    __builtin_amdgcn_s_barrier();                                               \
    /* phase 1: read A rows 64-127 of wave; stage other half of T+2 */          \
    bf16x8 af1[4];                                                              \
    _Pragma("unroll")                                                           \
    for (int t = 0; t < 4; t++)                                                 \
      af1[t] = ld_frag(bA + offA[4 + t]);                                       \
    if (pf) {                                                                   \
      async_cp16(gA + sga1 + k2, sA + db + 4096 + tid * 8);                     \
      async_cp16(gB + sga1 + k2, sB + db + 4096 + tid * 8);                     \
    }                                                                           \
    __builtin_amdgcn_s_barrier();                                               \
    asm volatile("s_waitcnt lgkmcnt(0)" ::: "memory");                          \
    __builtin_amdgcn_sched_barrier(0);                                          \
    __builtin_amdgcn_s_setprio(1);                                              \
    _Pragma("unroll")                                                           \
    for (int mt = 0; mt < 4; mt++)                                              \
      _Pragma("unroll")                                                         \
      for (int nt = 0; nt < 4; nt++)                                            \
        acc[4 + mt][nt] = __builtin_amdgcn_mfma_f32_16x16x32_bf16(af1[mt], bfv[nt], \
                                                                  acc[4 + mt][nt], 0, 0, 0); \
    __builtin_amdgcn_s_setprio(0);                                              \
    /* tile boundary: T+1 must be landed before next phase-0 ds_read.           \
       steady state: exactly T+2's 4 loads outstanding -> counted wait. */      \
    if (pf) { asm volatile("s_waitcnt vmcnt(4)" ::: "memory"); }                \
    else    { asm volatile("s_waitcnt vmcnt(0)" ::: "memory"); }                \
    __builtin_amdgcn_s_barrier();                                               \
  }

// ---- merged QKV GEMM with fused RoPE epilogue ----
__global__ __launch_bounds__(512, 2) void k_gemm_qkv(
    const uint16_t* __restrict__ xb, const uint16_t* __restrict__ wqkvb,
    uint16_t* __restrict__ Qb, uint16_t* __restrict__ Kb, uint16_t* __restrict__ Vb)
{
  const int bx = blockIdx.x;          // 0..23
  const int m0 = blockIdx.y * 256;
  const int n0 = bx * 256;            // weight row base (0..6143)
  G256_PROLOGUE(xb, wqkvb)

  const int region = (bx < 16) ? 0 : (bx < 20 ? 1 : 2);  // Q / K / V
  uint16_t* outp; int ldC, cbase;
  if (region == 0)      { outp = Qb; ldC = DIM;   cbase = n0; }
  else if (region == 1) { outp = Kb; ldC = KVDIM; cbase = n0 - 4096; }
  else                  { outp = Vb; ldC = KVDIM; cbase = n0 - 5120; }

  #pragma unroll
  for (int mt = 0; mt < 8; mt++)
    #pragma unroll
    for (int nt = 0; nt < 4; nt++) {
      const int col = cbase + wn + nt * 16 + l16;
      const int d = col & 127;
      const float freq = expf(-0.20503693f * (float)(d >> 1));
      const float sgn = (d & 1) ? 1.0f : -1.0f;
      #pragma unroll
      for (int r = 0; r < 4; r++) {
        const int row = m0 + wm + mt * 16 + quad * 4 + r;
        float v = acc[mt][nt][r];
        if (region < 2) {   // RoPE: pair lives in adjacent l16 lane
          float p = __shfl_xor(v, 1, 64);
          float ang = (float)row * freq;
          float sn, cs;
          sincosf(ang, &sn, &cs);
          v = v * cs + p * sn * sgn;
        }
        outp[(size_t)row * ldC + col] = f2bf(v);
      }
    }
}

// ---- O-projection GEMM (fp32 out) ----
__global__ __launch_bounds__(512, 2) void k_gemm_o(
    const uint16_t* __restrict__ ab, const uint16_t* __restrict__ wob,
    float* __restrict__ out)
{
  const int m0 = blockIdx.y * 256;
  const int n0 = blockIdx.x * 256;
  G256_PROLOGUE(ab, wob)
  #pragma unroll
  for (int mt = 0; mt < 8; mt++)
    #pragma unroll
    for (int nt = 0; nt < 4; nt++)
      #pragma unroll
      for (int r = 0; r < 4; r++) {
        int row = m0 + wm + mt * 16 + quad * 4 + r;
        int col = n0 + wn + nt * 16 + l16;
        out[(size_t)row * DIM + col] = acc[mt][nt][r];
      }
}

// ---------------- V transpose: V[s][kvh*128+d] -> VT[kvh][d][s] ----------------
__global__ __launch_bounds__(256) void k_vtrans(const uint16_t* __restrict__ Vb,
                                                uint16_t* __restrict__ VT) {
  __shared__ uint16_t t[64][72];
  const int s0 = blockIdx.x * 64;
  const int c0 = blockIdx.y * 64;
  const int tid = threadIdx.x;
  #pragma unroll
  for (int i = 0; i < 2; i++) {
    int idx = i * 256 + tid;
    int r = idx >> 3, ch = idx & 7;
    uint4 dv = *(const uint4*)(Vb + (size_t)(s0 + r) * KVDIM + c0 + ch * 8);
    *(uint4*)(&t[r][ch * 8]) = dv;
  }
  __syncthreads();
  const int kvh = c0 >> 7;
  const int dbase = c0 & 127;
  #pragma unroll
  for (int i = 0; i < 2; i++) {
    int idx = i * 256 + tid;
    int d = idx >> 3, sc = idx & 7;
    uint16_t tmp[8];
    #pragma unroll
    for (int j2 = 0; j2 < 8; j2++) tmp[j2] = t[sc * 8 + j2][d];
    *(uint4*)(VT + (size_t)kvh * HD * SEQ + (size_t)(dbase + d) * SEQ + s0 + sc * 8) = *(const uint4*)tmp;
  }
}

// ---------------- Split-KV flash attention, fixed-shift softmax ----------------
#define BKV 64
#define NPAIR 40
__device__ __constant__ uint8_t c_pair[NPAIR] = {
  12,16,20,24,28,29,32,33,36,37,40,41,44,45,46,48,49,50,52,53,54,56,57,58,60,61,62,63, // 8-iter
  8,25,42,59,   // 6-iter
  4,21,38,55,   // 4-iter
  0,17,34,51    // 2-iter
};
__device__ __constant__ uint8_t c_base[16] = {0,1,2,3,4,6,8,10,12,15,18,21,24,28,32,36};

__global__ __launch_bounds__(256) void k_flash_split(
    const uint16_t* __restrict__ Qb, const uint16_t* __restrict__ Kb,
    const uint16_t* __restrict__ VT, uint16_t* __restrict__ Opart,
    float* __restrict__ ml)
{
  const int pair = c_pair[blockIdx.x];
  const int qt   = pair >> 2;
  const int seg  = pair & 3;
  const int h    = blockIdx.y;
  const int kvh  = h >> 2;
  const int slot = h * NPAIR + c_base[qt] + seg;
  const int tid  = threadIdx.x;
  const int lane = tid & 63;
  const int wv   = tid >> 6;
  const int quad = lane >> 4;
  const int l16  = lane & 15;
  const int q0   = qt * 128;

  __shared__ __align__(16) uint16_t sK[BKV * 128];
  __shared__ __align__(16) uint16_t sVT[HD * BKV];
  __shared__ __align__(16) uint16_t sP[4 * 32 * 72];

  const uint16_t* Kbase  = Kb + kvh * HD;
  const uint16_t* VTbase = VT + (size_t)kvh * HD * SEQ;

  bf16x8 qf[2][4];
  #pragma unroll
  for (int mt = 0; mt < 2; mt++)
    #pragma unroll
    for (int ks = 0; ks < 4; ks++)
      qf[mt][ks] = ld_frag(Qb + (size_t)(q0 + wv * 32 + mt * 16 + l16) * DIM + h * HD + ks * 32 + quad * 8);

  __align__(16) uint16_t ones_bits[8];
  #pragma unroll
  for (int j = 0; j < 8; j++) ones_bits[j] = (l16 == 0) ? 0x3F80 : 0;
  const bf16x8 onesf = *(const bf16x8*)ones_bits;

  f32x4 Oacc[2][8] = {};
  f32x4 Lacc[2] = {};

  const float scale = 0.08838834764831845f;  // 1/sqrt(128)
  const float MFIX = 12.0f;
  const int j0 = seg * 8;
  const int j1 = min(j0 + 8, 2 * (qt + 1));

  for (int j = j0; j < j1; j++) {
    const int t0 = j * BKV;
    #pragma unroll
    for (int i = 0; i < 4; i++) {
      int pos = i * 256 + tid;
      int row = pos >> 4, g = (pos & 15) ^ (row & 7);
      async_cp16(Kbase + (size_t)(t0 + row) * KVDIM + g * 8, sK + pos * 8);
      int vrow = pos >> 3, vg = (pos & 7) ^ (vrow & 7);
      async_cp16(VTbase + (size_t)vrow * SEQ + t0 + vg * 8, sVT + pos * 8);
    }
    __syncthreads();

    bool active = (t0 <= q0 + wv * 32 + 31);  // wave-uniform
    if (active) {
      f32x4 Sacc[2][4] = {};
      #pragma unroll
      for (int ks = 0; ks < 4; ks++) {
        bf16x8 kf[4];
        #pragma unroll
        for (int nt = 0; nt < 4; nt++)
          kf[nt] = ld_frag(sK + (nt * 16 + l16) * 128 + (((ks * 4 + quad) ^ (l16 & 7)) * 8));
        #pragma unroll
        for (int mt = 0; mt < 2; mt++)
          #pragma unroll
          for (int nt = 0; nt < 4; nt++)
            Sacc[mt][nt] = __builtin_amdgcn_mfma_f32_16x16x32_bf16(qf[mt][ks], kf[nt], Sacc[mt][nt], 0, 0, 0);
      }
      const bool diag = (t0 + BKV - 1) > (q0 + wv * 32);
      #pragma unroll
      for (int mt = 0; mt < 2; mt++)
        #pragma unroll
        for (int nt = 0; nt < 4; nt++)
          #pragma unroll
          for (int r = 0; r < 4; r++) {
            float sv = Sacc[mt][nt][r] * scale - MFIX;
            bool msk = false;
            if (diag) {
              int qg = q0 + wv * 32 + mt * 16 + quad * 4 + r;
              int tg = t0 + nt * 16 + l16;
              msk = tg > qg;
            }
            float pv = msk ? 0.0f : __expf(sv);
            sP[(wv * 32 + mt * 16 + quad * 4 + r) * 72 + nt * 16 + l16] = f2bf(pv);
          }
      #pragma unroll
      for (int ks = 0; ks < 2; ks++) {
        bf16x8 pf[2], vf[8];
        #pragma unroll
        for (int mt = 0; mt < 2; mt++)
          pf[mt] = ld_frag(sP + (wv * 32 + mt * 16 + l16) * 72 + ks * 32 + quad * 8);
        #pragma unroll
        for (int dt = 0; dt < 8; dt++)
          vf[dt] = ld_frag(sVT + (dt * 16 + l16) * 64 + (((ks * 4 + quad) ^ (l16 & 7)) * 8));
        #pragma unroll
        for (int mt = 0; mt < 2; mt++) {
          Lacc[mt] = __builtin_amdgcn_mfma_f32_16x16x32_bf16(pf[mt], onesf, Lacc[mt], 0, 0, 0);
          #pragma unroll
          for (int dt = 0; dt < 8; dt++)
            Oacc[mt][dt] = __builtin_amdgcn_mfma_f32_16x16x32_bf16(pf[mt], vf[dt], Oacc[mt][dt], 0, 0, 0);
        }
      }
    }
    __syncthreads();
  }

  uint16_t* Op = Opart + (size_t)slot * (128 * 128);
  #pragma unroll
  for (int mt = 0; mt < 2; mt++)
    #pragma unroll
    for (int r = 0; r < 4; r++) {
      int row = wv * 32 + mt * 16 + quad * 4 + r;
      #pragma unroll
      for (int dt = 0; dt < 8; dt++)
        Op[row * 128 + dt * 16 + l16] = f2bf(Oacc[mt][dt][r]);
      if (l16 == 0)
        ml[(size_t)slot * 128 + row] = Lacc[mt][r];
    }
}

// ---------------- combine partials -> attn output (bf16) ----------------
__global__ __launch_bounds__(256) void k_combine(
    const uint16_t* __restrict__ Opart, const float* __restrict__ ml,
    uint16_t* __restrict__ attnb)
{
  const int qt = blockIdx.x;
  const int h  = blockIdx.y;
  const int nseg = (qt >> 2) + 1;
  const int slot0 = h * NPAIR + c_base[qt];
  const int tid = threadIdx.x;
  const int row = tid >> 1;
  const int dh  = (tid & 1) * 64;

  float L = 0.0f;
  #pragma unroll
  for (int i = 0; i < 4; i++)
    if (i < nseg) L += ml[(size_t)(slot0 + i) * 128 + row];
  const float invL = 1.0f / L;

  uint16_t* dst = attnb + (size_t)(qt * 128 + row) * DIM + h * HD + dh;
  #pragma unroll
  for (int c = 0; c < 8; c++) {
    int d = dh + c * 8;
    float acc[8] = {};
    #pragma unroll
    for (int i = 0; i < 4; i++) {
      if (i < nseg) {
        bf16x8 v = ld_frag(Opart + (size_t)(slot0 + i) * (128 * 128) + row * 128 + d);
        #pragma unroll
        for (int j = 0; j < 8; j++) acc[j] += (float)v[j];
      }
    }
    uint16_t outv[8];
    #pragma unroll
    for (int j = 0; j < 8; j++) outv[j] = f2bf(acc[j] * invL);
    *(uint4*)(dst + c * 8) = *(const uint4*)outv;
  }
}

// ---------------- launch ----------------
extern "C" void kernel_launch(void* const* d_in, const int* in_sizes, int n_in,
                              void* d_out, int out_size, void* d_ws, size_t ws_size,
                              hipStream_t stream) {
  const float* x  = (const float*)d_in[0];
  const float* wq = (const float*)d_in[1];
  const float* wk = (const float*)d_in[2];
  const float* wv = (const float*)d_in[3];
  const float* wo = (const float*)d_in[4];
  float* out = (float*)d_out;

  uint8_t* ws = (uint8_t*)d_ws;
  uint16_t* xb     = (uint16_t*)(ws + 0);
  uint16_t* wqkvb  = (uint16_t*)(ws + 16777216ull);
  uint16_t* Qb     = (uint16_t*)(ws + 67108864ull);
  uint16_t* Kb     = (uint16_t*)(ws + 83886080ull);
  uint16_t* Vb     = (uint16_t*)(ws + 88080384ull);
  uint16_t* VT     = (uint16_t*)(ws + 16777216ull);
  uint16_t* Opart  = (uint16_t*)(ws + 20971520ull);
  float*    mlbuf  = (float*)   (ws + 62914560ull);
  uint16_t* wob    = (uint16_t*)(ws + 16777216ull);
  uint16_t* attnb  = xb;

  k_conv_all<<<32768, 256, 0, stream>>>(x, wq, wk, wv, xb, wqkvb);
  k_gemm_qkv<<<dim3(24, 8), 512, 0, stream>>>(xb, wqkvb, Qb, Kb, Vb);
  k_vtrans<<<dim3(32, 16), 256, 0, stream>>>(Vb, VT);
  k_flash_split<<<dim3(NPAIR, 32), 256, 0, stream>>>(Qb, Kb, VT, Opart, mlbuf);
  k_combine<<<dim3(16, 32), 256, 0, stream>>>(Opart, mlbuf, attnb);
  k_conv<<<16384, 256, 0, stream>>>(wo, wob, 4194304);
  k_gemm_o<<<dim3(16, 8), 512, 0, stream>>>(attnb, wob, out);
}

// Round 4
// 613.534 us; speedup vs baseline: 1.0759x; 1.0212x over previous
//
#include <hip/hip_runtime.h>
#include <stdint.h>
#include <math.h>

#define SEQ   2048
#define DIM   4096
#define NHEAD 32
#define NKV   8
#define HD    128
#define KVDIM (NKV*HD)   // 1024

typedef __bf16 bf16x8 __attribute__((ext_vector_type(8)));
typedef float  f32x4  __attribute__((ext_vector_type(4)));

__device__ __forceinline__ uint16_t f2bf(float f) {
  uint32_t u = __float_as_uint(f);
  uint32_t r = (u + 0x7FFFu + ((u >> 16) & 1u)) >> 16;
  return (uint16_t)r;
}
__device__ __forceinline__ bf16x8 ld_frag(const uint16_t* p) {
  return *(const bf16x8*)p;
}
__device__ __forceinline__ void async_cp16(const void* g, void* lds) {
  __builtin_amdgcn_global_load_lds(
      (const __attribute__((address_space(1))) void*)g,
      (__attribute__((address_space(3))) void*)lds, 16, 0, 0);
}
// raw 32-bit LDS byte address (strips the generic-pointer aperture)
__device__ __forceinline__ uint32_t lds_u32(const void* p) {
  return (uint32_t)(uintptr_t)(const __attribute__((address_space(3))) void*)p;
}
// inline-asm ds_read_b128: opaque to the compiler's LDS-DMA waitcnt pass,
// so no auto-inserted vmcnt(0) drain before fragment reads. Ordering is
// enforced manually: our asm lgkmcnt(0) + sched_barrier(0) before MFMA,
// counted vmcnt + s_barrier at tile boundaries (ring distance 2 of 4).
__device__ __forceinline__ bf16x8 ds_read_b128a(uint32_t addr) {
  f32x4 r;
  asm volatile("ds_read_b128 %0, %1" : "=v"(r) : "v"(addr));
  return __builtin_bit_cast(bf16x8, r);
}

// ---------------- fused fp32 -> bf16 conversion: x, wq, wk, wv ----------------
__global__ __launch_bounds__(256) void k_conv_all(
    const float* __restrict__ x, const float* __restrict__ wq,
    const float* __restrict__ wk, const float* __restrict__ wv,
    uint16_t* __restrict__ xb, uint16_t* __restrict__ wqkvb) {
  size_t i = (size_t)blockIdx.x * 256 + threadIdx.x;   // float4 index, 8M total
  const float* s; uint16_t* d; size_t off;
  if (i < 2097152)      { s = x;  d = xb;                 off = i; }
  else if (i < 6291456) { s = wq; d = wqkvb;              off = i - 2097152; }
  else if (i < 7340032) { s = wk; d = wqkvb + 16777216u;  off = i - 6291456; }
  else                  { s = wv; d = wqkvb + 20971520u;  off = i - 7340032; }
  const float4 v = ((const float4*)s)[off];
  ushort4 o;
  o.x = f2bf(v.x); o.y = f2bf(v.y); o.z = f2bf(v.z); o.w = f2bf(v.w);
  ((ushort4*)d)[off] = o;
}

__global__ __launch_bounds__(256) void k_conv(const float* __restrict__ s,
                                              uint16_t* __restrict__ d, int n4) {
  int i = blockIdx.x * 256 + threadIdx.x;
  if (i >= n4) return;
  const float4 v = ((const float4*)s)[i];
  ushort4 o;
  o.x = f2bf(v.x); o.y = f2bf(v.y); o.z = f2bf(v.z); o.w = f2bf(v.w);
  ((ushort4*)d)[i] = o;
}

// ======================================================================
// 256x256 NT GEMM core, BK=32, 8 waves (2Mx4N), 4-deep LDS tile ring,
// counted vmcnt (never drains in steady state), setprio around MFMA,
// inline-asm ds_read_b128 fragment loads (no compiler DMA-hazard drains).
// LDS: 4 bufs x (256x32 A + 256x32 B) bf16 = 128 KiB.
// Swizzle: 16B chunk slot s of row r holds global chunk s ^ ((r>>1)&3)
// (pre-swizzled global source for global_load_lds + matching ds_read).
// ======================================================================
#define G256_TB   8192          /* elements per tile buffer (256*32) */

#define G256_PROLOGUE(Aptr, Bptr)                                               \
  __shared__ __align__(16) uint16_t sA[4 * G256_TB];                            \
  __shared__ __align__(16) uint16_t sB[4 * G256_TB];                            \
  const int tid  = threadIdx.x;                                                 \
  const int lane = tid & 63;                                                    \
  const int wv   = tid >> 6;                                                    \
  const int quad = lane >> 4;                                                   \
  const int l16  = lane & 15;                                                   \
  const int wm   = (wv >> 2) << 7;   /* 0 or 128 */                             \
  const int wn   = (wv & 3) << 6;    /* 0,64,128,192 */                         \
  const uint16_t* gA = Aptr + (size_t)m0 * DIM;                                 \
  const uint16_t* gB = Bptr + (size_t)n0 * DIM;                                 \
  const int srow0 = tid >> 2;                                                   \
  const int sc0   = (tid & 3) ^ ((srow0 >> 1) & 3);                             \
  const int srow1 = (512 + tid) >> 2;                                           \
  const int sc1   = (tid & 3) ^ ((srow1 >> 1) & 3);                             \
  const size_t sga0 = (size_t)srow0 * DIM + sc0 * 8;                            \
  const size_t sga1 = (size_t)srow1 * DIM + sc1 * 8;                            \
  const uint32_t sAb = lds_u32(sA);                                             \
  const uint32_t sBb = lds_u32(sB);                                             \
  uint32_t offA[8], offB[4];                                                    \
  _Pragma("unroll")                                                             \
  for (int t = 0; t < 8; t++) {                                                 \
    int r_ = wm + t * 16 + l16;                                                 \
    offA[t] = (uint32_t)((r_ * 32 + (quad ^ ((r_ >> 1) & 3)) * 8) * 2);         \
  }                                                                             \
  _Pragma("unroll")                                                             \
  for (int t = 0; t < 4; t++) {                                                 \
    int r_ = wn + t * 16 + l16;                                                 \
    offB[t] = (uint32_t)((r_ * 32 + (quad ^ ((r_ >> 1) & 3)) * 8) * 2);         \
  }                                                                             \
  f32x4 acc[8][4] = {};                                                         \
  /* prologue: stage tiles 0 and 1 */                                           \
  async_cp16(gA + sga0,      sA + tid * 8);                                     \
  async_cp16(gB + sga0,      sB + tid * 8);                                     \
  async_cp16(gA + sga1,      sA + 4096 + tid * 8);                              \
  async_cp16(gB + sga1,      sB + 4096 + tid * 8);                              \
  async_cp16(gA + sga0 + 32, sA + G256_TB + tid * 8);                           \
  async_cp16(gB + sga0 + 32, sB + G256_TB + tid * 8);                           \
  async_cp16(gA + sga1 + 32, sA + G256_TB + 4096 + tid * 8);                    \
  async_cp16(gB + sga1 + 32, sB + G256_TB + 4096 + tid * 8);                    \
  asm volatile("s_waitcnt vmcnt(4)" ::: "memory");  /* tile0 landed */          \
  __builtin_amdgcn_s_barrier();                                                 \
  for (int T = 0; T < 128; T++) {                                               \
    const uint32_t cbB  = (uint32_t)((T & 3) * (G256_TB * 2));                  \
    const uint32_t aBse = sAb + cbB;                                            \
    const uint32_t bBse = sBb + cbB;                                            \
    const int  k2 = (T + 2) * 32;                                               \
    const bool pf = (T + 2 < 128);                                              \
    const int  db = ((T + 2) & 3) * G256_TB;                                    \
    /* phase 0: read A rows 0-63 of wave + all B; stage half of T+2 */          \
    bf16x8 af0[4], bfv[4];                                                      \
    _Pragma("unroll")                                                           \
    for (int t = 0; t < 4; t++) {                                               \
      af0[t] = ds_read_b128a(aBse + offA[t]);                                   \
      bfv[t] = ds_read_b128a(bBse + offB[t]);                                   \
    }                                                                           \
    if (pf) {                                                                   \
      async_cp16(gA + sga0 + k2, sA + db + tid * 8);                            \
      async_cp16(gB + sga0 + k2, sB + db + tid * 8);                            \
    }                                                                           \
    __builtin_amdgcn_s_barrier();                                               \
    asm volatile("s_waitcnt lgkmcnt(0)" ::: "memory");                          \
    __builtin_amdgcn_sched_barrier(0);                                          \
    __builtin_amdgcn_s_setprio(1);                                              \
    _Pragma("unroll")                                                           \
    for (int mt = 0; mt < 4; mt++)                                              \
      _Pragma("unroll")                                                         \
      for (int nt = 0; nt < 4; nt++)                                            \
        acc[mt][nt] = __builtin_amdgcn_mfma_f32_16x16x32_bf16(af0[mt], bfv[nt], \
                                                              acc[mt][nt], 0, 0, 0); \
    __builtin_amdgcn_s_setprio(0);                                              \
    __builtin_amdgcn_s_barrier();                                               \
    /* phase 1: read A rows 64-127 of wave; stage other half of T+2 */          \
    bf16x8 af1[4];                                                              \
    _Pragma("unroll")                                                           \
    for (int t = 0; t < 4; t++)                                                 \
      af1[t] = ds_read_b128a(aBse + offA[4 + t]);                               \
    if (pf) {                                                                   \
      async_cp16(gA + sga1 + k2, sA + db + 4096 + tid * 8);                     \
      async_cp16(gB + sga1 + k2, sB + db + 4096 + tid * 8);                     \
    }                                                                           \
    __builtin_amdgcn_s_barrier();                                               \
    asm volatile("s_waitcnt lgkmcnt(0)" ::: "memory");                          \
    __builtin_amdgcn_sched_barrier(0);                                          \
    __builtin_amdgcn_s_setprio(1);                                              \
    _Pragma("unroll")                                                           \
    for (int mt = 0; mt < 4; mt++)                                              \
      _Pragma("unroll")                                                         \
      for (int nt = 0; nt < 4; nt++)                                            \
        acc[4 + mt][nt] = __builtin_amdgcn_mfma_f32_16x16x32_bf16(af1[mt], bfv[nt], \
                                                                  acc[4 + mt][nt], 0, 0, 0); \
    __builtin_amdgcn_s_setprio(0);                                              \
    /* tile boundary: wave-local vmcnt then barrier => buf[T+1] block-valid.    \
       steady state: exactly T+2's 4 loads outstanding -> counted wait. */      \
    if (pf) { asm volatile("s_waitcnt vmcnt(4)" ::: "memory"); }                \
    else    { asm volatile("s_waitcnt vmcnt(0)" ::: "memory"); }                \
    __builtin_amdgcn_s_barrier();                                               \
  }

// ---- merged QKV GEMM with fused RoPE epilogue ----
__global__ __launch_bounds__(512, 2) void k_gemm_qkv(
    const uint16_t* __restrict__ xb, const uint16_t* __restrict__ wqkvb,
    uint16_t* __restrict__ Qb, uint16_t* __restrict__ Kb, uint16_t* __restrict__ Vb)
{
  const int bx = blockIdx.x;          // 0..23
  const int m0 = blockIdx.y * 256;
  const int n0 = bx * 256;            // weight row base (0..6143)
  G256_PROLOGUE(xb, wqkvb)

  const int region = (bx < 16) ? 0 : (bx < 20 ? 1 : 2);  // Q / K / V
  uint16_t* outp; int ldC, cbase;
  if (region == 0)      { outp = Qb; ldC = DIM;   cbase = n0; }
  else if (region == 1) { outp = Kb; ldC = KVDIM; cbase = n0 - 4096; }
  else                  { outp = Vb; ldC = KVDIM; cbase = n0 - 5120; }

  #pragma unroll
  for (int mt = 0; mt < 8; mt++)
    #pragma unroll
    for (int nt = 0; nt < 4; nt++) {
      const int col = cbase + wn + nt * 16 + l16;
      const int d = col & 127;
      const float freq = expf(-0.20503693f * (float)(d >> 1));
      const float sgn = (d & 1) ? 1.0f : -1.0f;
      #pragma unroll
      for (int r = 0; r < 4; r++) {
        const int row = m0 + wm + mt * 16 + quad * 4 + r;
        float v = acc[mt][nt][r];
        if (region < 2) {   // RoPE: pair lives in adjacent l16 lane
          float p = __shfl_xor(v, 1, 64);
          float ang = (float)row * freq;
          float sn, cs;
          sincosf(ang, &sn, &cs);
          v = v * cs + p * sn * sgn;
        }
        outp[(size_t)row * ldC + col] = f2bf(v);
      }
    }
}

// ---- O-projection GEMM (fp32 out) ----
__global__ __launch_bounds__(512, 2) void k_gemm_o(
    const uint16_t* __restrict__ ab, const uint16_t* __restrict__ wob,
    float* __restrict__ out)
{
  const int m0 = blockIdx.y * 256;
  const int n0 = blockIdx.x * 256;
  G256_PROLOGUE(ab, wob)
  #pragma unroll
  for (int mt = 0; mt < 8; mt++)
    #pragma unroll
    for (int nt = 0; nt < 4; nt++)
      #pragma unroll
      for (int r = 0; r < 4; r++) {
        int row = m0 + wm + mt * 16 + quad * 4 + r;
        int col = n0 + wn + nt * 16 + l16;
        out[(size_t)row * DIM + col] = acc[mt][nt][r];
      }
}

// ---------------- V transpose: V[s][kvh*128+d] -> VT[kvh][d][s] ----------------
__global__ __launch_bounds__(256) void k_vtrans(const uint16_t* __restrict__ Vb,
                                                uint16_t* __restrict__ VT) {
  __shared__ uint16_t t[64][72];
  const int s0 = blockIdx.x * 64;
  const int c0 = blockIdx.y * 64;
  const int tid = threadIdx.x;
  #pragma unroll
  for (int i = 0; i < 2; i++) {
    int idx = i * 256 + tid;
    int r = idx >> 3, ch = idx & 7;
    uint4 dv = *(const uint4*)(Vb + (size_t)(s0 + r) * KVDIM + c0 + ch * 8);
    *(uint4*)(&t[r][ch * 8]) = dv;
  }
  __syncthreads();
  const int kvh = c0 >> 7;
  const int dbase = c0 & 127;
  #pragma unroll
  for (int i = 0; i < 2; i++) {
    int idx = i * 256 + tid;
    int d = idx >> 3, sc = idx & 7;
    uint16_t tmp[8];
    #pragma unroll
    for (int j2 = 0; j2 < 8; j2++) tmp[j2] = t[sc * 8 + j2][d];
    *(uint4*)(VT + (size_t)kvh * HD * SEQ + (size_t)(dbase + d) * SEQ + s0 + sc * 8) = *(const uint4*)tmp;
  }
}

// ---------------- Split-KV flash attention, fixed-shift softmax ----------------
#define BKV 64
#define NPAIR 40
__device__ __constant__ uint8_t c_pair[NPAIR] = {
  12,16,20,24,28,29,32,33,36,37,40,41,44,45,46,48,49,50,52,53,54,56,57,58,60,61,62,63, // 8-iter
  8,25,42,59,   // 6-iter
  4,21,38,55,   // 4-iter
  0,17,34,51    // 2-iter
};
__device__ __constant__ uint8_t c_base[16] = {0,1,2,3,4,6,8,10,12,15,18,21,24,28,32,36};

__global__ __launch_bounds__(256) void k_flash_split(
    const uint16_t* __restrict__ Qb, const uint16_t* __restrict__ Kb,
    const uint16_t* __restrict__ VT, uint16_t* __restrict__ Opart,
    float* __restrict__ ml)
{
  const int pair = c_pair[blockIdx.x];
  const int qt   = pair >> 2;
  const int seg  = pair & 3;
  const int h    = blockIdx.y;
  const int kvh  = h >> 2;
  const int slot = h * NPAIR + c_base[qt] + seg;
  const int tid  = threadIdx.x;
  const int lane = tid & 63;
  const int wv   = tid >> 6;
  const int quad = lane >> 4;
  const int l16  = lane & 15;
  const int q0   = qt * 128;

  __shared__ __align__(16) uint16_t sK[BKV * 128];
  __shared__ __align__(16) uint16_t sVT[HD * BKV];
  __shared__ __align__(16) uint16_t sP[4 * 32 * 72];

  const uint16_t* Kbase  = Kb + kvh * HD;
  const uint16_t* VTbase = VT + (size_t)kvh * HD * SEQ;

  bf16x8 qf[2][4];
  #pragma unroll
  for (int mt = 0; mt < 2; mt++)
    #pragma unroll
    for (int ks = 0; ks < 4; ks++)
      qf[mt][ks] = ld_frag(Qb + (size_t)(q0 + wv * 32 + mt * 16 + l16) * DIM + h * HD + ks * 32 + quad * 8);

  __align__(16) uint16_t ones_bits[8];
  #pragma unroll
  for (int j = 0; j < 8; j++) ones_bits[j] = (l16 == 0) ? 0x3F80 : 0;
  const bf16x8 onesf = *(const bf16x8*)ones_bits;

  f32x4 Oacc[2][8] = {};
  f32x4 Lacc[2] = {};

  const float scale = 0.08838834764831845f;  // 1/sqrt(128)
  const float MFIX = 12.0f;
  const int j0 = seg * 8;
  const int j1 = min(j0 + 8, 2 * (qt + 1));

  for (int j = j0; j < j1; j++) {
    const int t0 = j * BKV;
    #pragma unroll
    for (int i = 0; i < 4; i++) {
      int pos = i * 256 + tid;
      int row = pos >> 4, g = (pos & 15) ^ (row & 7);
      async_cp16(Kbase + (size_t)(t0 + row) * KVDIM + g * 8, sK + pos * 8);
      int vrow = pos >> 3, vg = (pos & 7) ^ (vrow & 7);
      async_cp16(VTbase + (size_t)vrow * SEQ + t0 + vg * 8, sVT + pos * 8);
    }
    __syncthreads();

    bool active = (t0 <= q0 + wv * 32 + 31);  // wave-uniform
    if (active) {
      f32x4 Sacc[2][4] = {};
      #pragma unroll
      for (int ks = 0; ks < 4; ks++) {
        bf16x8 kf[4];
        #pragma unroll
        for (int nt = 0; nt < 4; nt++)
          kf[nt] = ld_frag(sK + (nt * 16 + l16) * 128 + (((ks * 4 + quad) ^ (l16 & 7)) * 8));
        #pragma unroll
        for (int mt = 0; mt < 2; mt++)
          #pragma unroll
          for (int nt = 0; nt < 4; nt++)
            Sacc[mt][nt] = __builtin_amdgcn_mfma_f32_16x16x32_bf16(qf[mt][ks], kf[nt], Sacc[mt][nt], 0, 0, 0);
      }
      const bool diag = (t0 + BKV - 1) > (q0 + wv * 32);
      #pragma unroll
      for (int mt = 0; mt < 2; mt++)
        #pragma unroll
        for (int nt = 0; nt < 4; nt++)
          #pragma unroll
          for (int r = 0; r < 4; r++) {
            float sv = Sacc[mt][nt][r] * scale - MFIX;
            bool msk = false;
            if (diag) {
              int qg = q0 + wv * 32 + mt * 16 + quad * 4 + r;
              int tg = t0 + nt * 16 + l16;
              msk = tg > qg;
            }
            float pv = msk ? 0.0f : __expf(sv);
            sP[(wv * 32 + mt * 16 + quad * 4 + r) * 72 + nt * 16 + l16] = f2bf(pv);
          }
      #pragma unroll
      for (int ks = 0; ks < 2; ks++) {
        bf16x8 pf[2], vf[8];
        #pragma unroll
        for (int mt = 0; mt < 2; mt++)
          pf[mt] = ld_frag(sP + (wv * 32 + mt * 16 + l16) * 72 + ks * 32 + quad * 8);
        #pragma unroll
        for (int dt = 0; dt < 8; dt++)
          vf[dt] = ld_frag(sVT + (dt * 16 + l16) * 64 + (((ks * 4 + quad) ^ (l16 & 7)) * 8));
        #pragma unroll
        for (int mt = 0; mt < 2; mt++) {
          Lacc[mt] = __builtin_amdgcn_mfma_f32_16x16x32_bf16(pf[mt], onesf, Lacc[mt], 0, 0, 0);
          #pragma unroll
          for (int dt = 0; dt < 8; dt++)
            Oacc[mt][dt] = __builtin_amdgcn_mfma_f32_16x16x32_bf16(pf[mt], vf[dt], Oacc[mt][dt], 0, 0, 0);
        }
      }
    }
    __syncthreads();
  }

  uint16_t* Op = Opart + (size_t)slot * (128 * 128);
  #pragma unroll
  for (int mt = 0; mt < 2; mt++)
    #pragma unroll
    for (int r = 0; r < 4; r++) {
      int row = wv * 32 + mt * 16 + quad * 4 + r;
      #pragma unroll
      for (int dt = 0; dt < 8; dt++)
        Op[row * 128 + dt * 16 + l16] = f2bf(Oacc[mt][dt][r]);
      if (l16 == 0)
        ml[(size_t)slot * 128 + row] = Lacc[mt][r];
    }
}

// ---------------- combine partials -> attn output (bf16) ----------------
__global__ __launch_bounds__(256) void k_combine(
    const uint16_t* __restrict__ Opart, const float* __restrict__ ml,
    uint16_t* __restrict__ attnb)
{
  const int qt = blockIdx.x;
  const int h  = blockIdx.y;
  const int nseg = (qt >> 2) + 1;
  const int slot0 = h * NPAIR + c_base[qt];
  const int tid = threadIdx.x;
  const int row = tid >> 1;
  const int dh  = (tid & 1) * 64;

  float L = 0.0f;
  #pragma unroll
  for (int i = 0; i < 4; i++)
    if (i < nseg) L += ml[(size_t)(slot0 + i) * 128 + row];
  const float invL = 1.0f / L;

  uint16_t* dst = attnb + (size_t)(qt * 128 + row) * DIM + h * HD + dh;
  #pragma unroll
  for (int c = 0; c < 8; c++) {
    int d = dh + c * 8;
    float acc[8] = {};
    #pragma unroll
    for (int i = 0; i < 4; i++) {
      if (i < nseg) {
        bf16x8 v = ld_frag(Opart + (size_t)(slot0 + i) * (128 * 128) + row * 128 + d);
        #pragma unroll
        for (int j = 0; j < 8; j++) acc[j] += (float)v[j];
      }
    }
    uint16_t outv[8];
    #pragma unroll
    for (int j = 0; j < 8; j++) outv[j] = f2bf(acc[j] * invL);
    *(uint4*)(dst + c * 8) = *(const uint4*)outv;
  }
}

// ---------------- launch ----------------
extern "C" void kernel_launch(void* const* d_in, const int* in_sizes, int n_in,
                              void* d_out, int out_size, void* d_ws, size_t ws_size,
                              hipStream_t stream) {
  const float* x  = (const float*)d_in[0];
  const float* wq = (const float*)d_in[1];
  const float* wk = (const float*)d_in[2];
  const float* wv = (const float*)d_in[3];
  const float* wo = (const float*)d_in[4];
  float* out = (float*)d_out;

  uint8_t* ws = (uint8_t*)d_ws;
  uint16_t* xb     = (uint16_t*)(ws + 0);
  uint16_t* wqkvb  = (uint16_t*)(ws + 16777216ull);
  uint16_t* Qb     = (uint16_t*)(ws + 67108864ull);
  uint16_t* Kb     = (uint16_t*)(ws + 83886080ull);
  uint16_t* Vb     = (uint16_t*)(ws + 88080384ull);
  uint16_t* VT     = (uint16_t*)(ws + 16777216ull);
  uint16_t* Opart  = (uint16_t*)(ws + 20971520ull);
  float*    mlbuf  = (float*)   (ws + 62914560ull);
  uint16_t* wob    = (uint16_t*)(ws + 16777216ull);
  uint16_t* attnb  = xb;

  k_conv_all<<<32768, 256, 0, stream>>>(x, wq, wk, wv, xb, wqkvb);
  k_gemm_qkv<<<dim3(24, 8), 512, 0, stream>>>(xb, wqkvb, Qb, Kb, Vb);
  k_vtrans<<<dim3(32, 16), 256, 0, stream>>>(Vb, VT);
  k_flash_split<<<dim3(NPAIR, 32), 256, 0, stream>>>(Qb, Kb, VT, Opart, mlbuf);
  k_combine<<<dim3(16, 32), 256, 0, stream>>>(Opart, mlbuf, attnb);
  k_conv<<<16384, 256, 0, stream>>>(wo, wob, 4194304);
  k_gemm_o<<<dim3(16, 8), 512, 0, stream>>>(attnb, wob, out);
}

// Round 6
// 608.026 us; speedup vs baseline: 1.0856x; 1.0091x over previous
//
#include <hip/hip_runtime.h>
#include <stdint.h>
#include <math.h>

#define SEQ   2048
#define DIM   4096
#define NHEAD 32
#define NKV   8
#define HD    128
#define KVDIM (NKV*HD)   // 1024

typedef __bf16 bf16x8 __attribute__((ext_vector_type(8)));
typedef float  f32x4  __attribute__((ext_vector_type(4)));

__device__ __forceinline__ uint16_t f2bf(float f) {
  uint32_t u = __float_as_uint(f);
  uint32_t r = (u + 0x7FFFu + ((u >> 16) & 1u)) >> 16;
  return (uint16_t)r;
}
__device__ __forceinline__ bf16x8 ld_frag(const uint16_t* p) {
  return *(const bf16x8*)p;
}
__device__ __forceinline__ void async_cp16(const void* g, void* lds) {
  __builtin_amdgcn_global_load_lds(
      (const __attribute__((address_space(1))) void*)g,
      (__attribute__((address_space(3))) void*)lds, 16, 0, 0);
}
__device__ __forceinline__ uint32_t lds_u32(const void* p) {
  return (uint32_t)(uintptr_t)(const __attribute__((address_space(3))) void*)p;
}
__device__ __forceinline__ bf16x8 ds_read_b128a(uint32_t addr) {
  f32x4 r;
  asm volatile("ds_read_b128 %0, %1" : "=v"(r) : "v"(addr));
  return __builtin_bit_cast(bf16x8, r);
}

// ---------------- fused fp32 -> bf16 conversion: x, wq, wk, wv ----------------
__global__ __launch_bounds__(256) void k_conv_all(
    const float* __restrict__ x, const float* __restrict__ wq,
    const float* __restrict__ wk, const float* __restrict__ wv,
    uint16_t* __restrict__ xb, uint16_t* __restrict__ wqkvb) {
  size_t i = (size_t)blockIdx.x * 256 + threadIdx.x;   // float4 index, 8M total
  const float* s; uint16_t* d; size_t off;
  if (i < 2097152)      { s = x;  d = xb;                 off = i; }
  else if (i < 6291456) { s = wq; d = wqkvb;              off = i - 2097152; }
  else if (i < 7340032) { s = wk; d = wqkvb + 16777216u;  off = i - 6291456; }
  else                  { s = wv; d = wqkvb + 20971520u;  off = i - 7340032; }
  const float4 v = ((const float4*)s)[off];
  ushort4 o;
  o.x = f2bf(v.x); o.y = f2bf(v.y); o.z = f2bf(v.z); o.w = f2bf(v.w);
  ((ushort4*)d)[off] = o;
}

__global__ __launch_bounds__(256) void k_conv(const float* __restrict__ s,
                                              uint16_t* __restrict__ d, int n4) {
  int i = blockIdx.x * 256 + threadIdx.x;
  if (i >= n4) return;
  const float4 v = ((const float4*)s)[i];
  ushort4 o;
  o.x = f2bf(v.x); o.y = f2bf(v.y); o.z = f2bf(v.z); o.w = f2bf(v.w);
  ((ushort4*)d)[i] = o;
}

// ======================================================================
// 256x256 NT GEMM core, BK=64, 8 waves (2Mx4N, wave tile 128x64),
// 4-phase/K-tile schedule with counted vmcnt. Stage groups are aligned
// to per-phase READ sets (union over all waves):
//   A-even = rows {0-63,128-191}   read in P0 -> staged in P0 (prev tile)
//   B-q0   = rows {g..g+31}        read in P0 -> staged in P1
//   B-q1   = rows {g+32..g+63}     read in P1 -> staged in P2
//   A-odd  = rows {64-127,192-255} read in P2 -> staged in P3
// Waits: endP3 vmcnt(4) [A-even'+B-q0' landed], endP0 vmcnt(4) [B-q1],
// endP1 vmcnt(4) [A-odd], endP2 none. Never drains in steady state.
// LDS: 2 K-tile double buffer x (256x64 A + 256x64 B) bf16 = 128 KiB;
// row r at element r*64 (layout unchanged; only stage ORDER regrouped).
// Swizzle: 16B chunk slot c' of row r holds global chunk c' ^ (r&7)
// (pre-swizzled global source for cp16, matching XOR on ds_read).
// Tile 64 prefetch (T=63) is a harmless in-bounds workspace over-read.
// ======================================================================

#define STG2(gX, sX, row1g, halfel, Tn) do {                                    \
    async_cp16(gX + (size_t)(row1g) * DIM + (size_t)(Tn) * 64 + cchunk * 8,     \
               sX + (halfel) + (row1g) * 64 + (tid & 7) * 8);                   \
    async_cp16(gX + (size_t)((row1g) + 128) * DIM + (size_t)(Tn) * 64 + cchunk * 8, \
               sX + (halfel) + ((row1g) + 128) * 64 + (tid & 7) * 8);           \
  } while (0)

#define G256_PROLOGUE(Aptr, Bptr)                                               \
  __shared__ __align__(16) uint16_t sA[2 * 16384];                              \
  __shared__ __align__(16) uint16_t sB[2 * 16384];                              \
  const int tid  = threadIdx.x;                                                 \
  const int lane = tid & 63;                                                    \
  const int wv   = tid >> 6;                                                    \
  const int quad = lane >> 4;                                                   \
  const int l16  = lane & 15;                                                   \
  const int wm   = (wv >> 2) << 7;   /* 0 or 128 */                             \
  const int wn   = (wv & 3) << 6;    /* 0,64,128,192 */                         \
  const uint16_t* gA = Aptr + (size_t)m0 * DIM;                                 \
  const uint16_t* gB = Bptr + (size_t)n0 * DIM;                                 \
  const int crow   = tid >> 3;                                                  \
  const int cchunk = (tid & 7) ^ (crow & 7);                                    \
  const int rA0 = crow;                              /* A-even: r, r+128 */     \
  const int rA1 = crow + 64;                         /* A-odd:  r, r+128 */     \
  const int rB0 = ((crow >> 5) << 6) + (crow & 31);  /* B-q0:   r, r+128 */     \
  const int rB1 = rB0 + 32;                          /* B-q1:   r, r+128 */     \
  const uint32_t sAb = lds_u32(sA);                                             \
  const uint32_t sBb = lds_u32(sB);                                             \
  uint32_t rowbA[4], rowbB[2], colb[2];                                         \
  _Pragma("unroll")                                                             \
  for (int t = 0; t < 4; t++) rowbA[t] = (uint32_t)((wm + t * 16 + l16) * 128); \
  _Pragma("unroll")                                                             \
  for (int u = 0; u < 2; u++) rowbB[u] = (uint32_t)((wn + u * 16 + l16) * 128); \
  _Pragma("unroll")                                                             \
  for (int ks = 0; ks < 2; ks++)                                                \
    colb[ks] = (uint32_t)((((ks * 4 + quad) ^ (l16 & 7)) * 16));                \
  f32x4 acc[8][4] = {};                                                         \
  bf16x8 af[4][2], bf0[2][2], bf1[2][2];                                        \
  /* prologue: stage tile 0 in read-order A-even, B-q0, B-q1, A-odd */          \
  STG2(gA, sA, rA0, 0, 0);                                                      \
  STG2(gB, sB, rB0, 0, 0);                                                      \
  STG2(gB, sB, rB1, 0, 0);                                                      \
  STG2(gA, sA, rA1, 0, 0);                                                      \
  asm volatile("s_waitcnt vmcnt(4)" ::: "memory");  /* A-even+B-q0 landed */    \
  __builtin_amdgcn_s_barrier();                                                 \
  for (int T = 0; T < 64; T++) {                                                \
    const uint32_t dsel   = (uint32_t)((T & 1) << 15);   /* read buf, bytes */  \
    const int      halfel = ((T + 1) & 1) << 14;         /* write buf, elems */ \
    const int      Tn     = T + 1;                                              \
    /* ---- P0: quadrant (Mh0,Nh0); reads A-even(8) + B-q0(4); stage A-even' */ \
    _Pragma("unroll")                                                           \
    for (int t = 0; t < 4; t++) {                                               \
      af[t][0] = ds_read_b128a(sAb + dsel + rowbA[t] + colb[0]);                \
      af[t][1] = ds_read_b128a(sAb + dsel + rowbA[t] + colb[1]);                \
    }                                                                           \
    _Pragma("unroll")                                                           \
    for (int u = 0; u < 2; u++) {                                               \
      bf0[u][0] = ds_read_b128a(sBb + dsel + rowbB[u] + colb[0]);               \
      bf0[u][1] = ds_read_b128a(sBb + dsel + rowbB[u] + colb[1]);               \
    }                                                                           \
    STG2(gA, sA, rA0, halfel, Tn);                                              \
    __builtin_amdgcn_s_barrier();                                               \
    asm volatile("s_waitcnt lgkmcnt(0)" ::: "memory");                          \
    __builtin_amdgcn_sched_barrier(0);                                          \
    __builtin_amdgcn_s_setprio(1);                                              \
    _Pragma("unroll")                                                           \
    for (int ks = 0; ks < 2; ks++)                                              \
      _Pragma("unroll")                                                         \
      for (int t = 0; t < 4; t++)                                               \
        _Pragma("unroll")                                                       \
        for (int u = 0; u < 2; u++)                                             \
          acc[t][u] = __builtin_amdgcn_mfma_f32_16x16x32_bf16(af[t][ks], bf0[u][ks], acc[t][u], 0, 0, 0); \
    __builtin_amdgcn_s_setprio(0);                                              \
    asm volatile("s_waitcnt vmcnt(4)" ::: "memory");   /* B-q1 landed */        \
    __builtin_amdgcn_s_barrier();                                               \
    /* ---- P1: quadrant (Mh0,Nh1); reads B-q1(4); stage B-q0' ---- */          \
    _Pragma("unroll")                                                           \
    for (int u = 0; u < 2; u++) {                                               \
      bf1[u][0] = ds_read_b128a(sBb + dsel + 4096 + rowbB[u] + colb[0]);        \
      bf1[u][1] = ds_read_b128a(sBb + dsel + 4096 + rowbB[u] + colb[1]);        \
    }                                                                           \
    STG2(gB, sB, rB0, halfel, Tn);                                              \
    __builtin_amdgcn_s_barrier();                                               \
    asm volatile("s_waitcnt lgkmcnt(0)" ::: "memory");                          \
    __builtin_amdgcn_sched_barrier(0);                                          \
    __builtin_amdgcn_s_setprio(1);                                              \
    _Pragma("unroll")                                                           \
    for (int ks = 0; ks < 2; ks++)                                              \
      _Pragma("unroll")                                                         \
      for (int t = 0; t < 4; t++)                                               \
        _Pragma("unroll")                                                       \
        for (int u = 0; u < 2; u++)                                             \
          acc[t][2 + u] = __builtin_amdgcn_mfma_f32_16x16x32_bf16(af[t][ks], bf1[u][ks], acc[t][2 + u], 0, 0, 0); \
    __builtin_amdgcn_s_setprio(0);                                              \
    asm volatile("s_waitcnt vmcnt(4)" ::: "memory");   /* A-odd landed */       \
    __builtin_amdgcn_s_barrier();                                               \
    /* ---- P2: quadrant (Mh1,Nh0); reads A-odd(8); stage B-q1' ---- */         \
    _Pragma("unroll")                                                           \
    for (int t = 0; t < 4; t++) {                                               \
      af[t][0] = ds_read_b128a(sAb + dsel + 8192 + rowbA[t] + colb[0]);         \
      af[t][1] = ds_read_b128a(sAb + dsel + 8192 + rowbA[t] + colb[1]);         \
    }                                                                           \
    STG2(gB, sB, rB1, halfel, Tn);                                              \
    __builtin_amdgcn_s_barrier();                                               \
    asm volatile("s_waitcnt lgkmcnt(0)" ::: "memory");                          \
    __builtin_amdgcn_sched_barrier(0);                                          \
    __builtin_amdgcn_s_setprio(1);                                              \
    _Pragma("unroll")                                                           \
    for (int ks = 0; ks < 2; ks++)                                              \
      _Pragma("unroll")                                                         \
      for (int t = 0; t < 4; t++)                                               \
        _Pragma("unroll")                                                       \
        for (int u = 0; u < 2; u++)                                             \
          acc[4 + t][u] = __builtin_amdgcn_mfma_f32_16x16x32_bf16(af[t][ks], bf0[u][ks], acc[4 + t][u], 0, 0, 0); \
    __builtin_amdgcn_s_setprio(0);                                              \
    __builtin_amdgcn_s_barrier();                                               \
    /* ---- P3: quadrant (Mh1,Nh1); no new reads; stage A-odd' ---- */          \
    STG2(gA, sA, rA1, halfel, Tn);                                              \
    __builtin_amdgcn_s_barrier();                                               \
    __builtin_amdgcn_sched_barrier(0);                                          \
    __builtin_amdgcn_s_setprio(1);                                              \
    _Pragma("unroll")                                                           \
    for (int ks = 0; ks < 2; ks++)                                              \
      _Pragma("unroll")                                                         \
      for (int t = 0; t < 4; t++)                                               \
        _Pragma("unroll")                                                       \
        for (int u = 0; u < 2; u++)                                             \
          acc[4 + t][2 + u] = __builtin_amdgcn_mfma_f32_16x16x32_bf16(af[t][ks], bf1[u][ks], acc[4 + t][2 + u], 0, 0, 0); \
    __builtin_amdgcn_s_setprio(0);                                              \
    asm volatile("s_waitcnt vmcnt(4)" ::: "memory");   /* A-even'+B-q0' */      \
    __builtin_amdgcn_s_barrier();                                               \
  }                                                                             \
  asm volatile("s_waitcnt vmcnt(0)" ::: "memory");

// ---- merged QKV GEMM with fused RoPE epilogue ----
__global__ __launch_bounds__(512, 2) void k_gemm_qkv(
    const uint16_t* __restrict__ xb, const uint16_t* __restrict__ wqkvb,
    uint16_t* __restrict__ Qb, uint16_t* __restrict__ Kb, uint16_t* __restrict__ Vb)
{
  const int bx = blockIdx.x;          // 0..23
  const int m0 = blockIdx.y * 256;
  const int n0 = bx * 256;            // weight row base (0..6143)
  G256_PROLOGUE(xb, wqkvb)

  const int region = (bx < 16) ? 0 : (bx < 20 ? 1 : 2);  // Q / K / V
  uint16_t* outp; int ldC, cbase;
  if (region == 0)      { outp = Qb; ldC = DIM;   cbase = n0; }
  else if (region == 1) { outp = Kb; ldC = KVDIM; cbase = n0 - 4096; }
  else                  { outp = Vb; ldC = KVDIM; cbase = n0 - 5120; }

  #pragma unroll
  for (int mh = 0; mh < 2; mh++)
    #pragma unroll
    for (int t = 0; t < 4; t++)
      #pragma unroll
      for (int nh = 0; nh < 2; nh++)
        #pragma unroll
        for (int u = 0; u < 2; u++) {
          const int col = cbase + wn + nh * 32 + u * 16 + l16;
          const int d = col & 127;
          const float freq = expf(-0.20503693f * (float)(d >> 1));
          const float sgn = (d & 1) ? 1.0f : -1.0f;
          #pragma unroll
          for (int r = 0; r < 4; r++) {
            const int row = m0 + wm + mh * 64 + t * 16 + quad * 4 + r;
            float v = acc[mh * 4 + t][nh * 2 + u][r];
            if (region < 2) {   // RoPE: pair lives in adjacent l16 lane
              float p = __shfl_xor(v, 1, 64);
              float ang = (float)row * freq;
              float sn, cs;
              sincosf(ang, &sn, &cs);
              v = v * cs + p * sn * sgn;
            }
            outp[(size_t)row * ldC + col] = f2bf(v);
          }
        }
}

// ---- O-projection GEMM (fp32 out) ----
__global__ __launch_bounds__(512, 2) void k_gemm_o(
    const uint16_t* __restrict__ ab, const uint16_t* __restrict__ wob,
    float* __restrict__ out)
{
  const int m0 = blockIdx.y * 256;
  const int n0 = blockIdx.x * 256;
  G256_PROLOGUE(ab, wob)
  #pragma unroll
  for (int mh = 0; mh < 2; mh++)
    #pragma unroll
    for (int t = 0; t < 4; t++)
      #pragma unroll
      for (int nh = 0; nh < 2; nh++)
        #pragma unroll
        for (int u = 0; u < 2; u++)
          #pragma unroll
          for (int r = 0; r < 4; r++) {
            int row = m0 + wm + mh * 64 + t * 16 + quad * 4 + r;
            int col = n0 + wn + nh * 32 + u * 16 + l16;
            out[(size_t)row * DIM + col] = acc[mh * 4 + t][nh * 2 + u][r];
          }
}

// ---------------- V transpose: V[s][kvh*128+d] -> VT[kvh][d][s] ----------------
__global__ __launch_bounds__(256) void k_vtrans(const uint16_t* __restrict__ Vb,
                                                uint16_t* __restrict__ VT) {
  __shared__ uint16_t t[64][72];
  const int s0 = blockIdx.x * 64;
  const int c0 = blockIdx.y * 64;
  const int tid = threadIdx.x;
  #pragma unroll
  for (int i = 0; i < 2; i++) {
    int idx = i * 256 + tid;
    int r = idx >> 3, ch = idx & 7;
    uint4 dv = *(const uint4*)(Vb + (size_t)(s0 + r) * KVDIM + c0 + ch * 8);
    *(uint4*)(&t[r][ch * 8]) = dv;
  }
  __syncthreads();
  const int kvh = c0 >> 7;
  const int dbase = c0 & 127;
  #pragma unroll
  for (int i = 0; i < 2; i++) {
    int idx = i * 256 + tid;
    int d = idx >> 3, sc = idx & 7;
    uint16_t tmp[8];
    #pragma unroll
    for (int j2 = 0; j2 < 8; j2++) tmp[j2] = t[sc * 8 + j2][d];
    *(uint4*)(VT + (size_t)kvh * HD * SEQ + (size_t)(dbase + d) * SEQ + s0 + sc * 8) = *(const uint4*)tmp;
  }
}

// ---------------- Split-KV flash attention, fixed-shift softmax ----------------
#define BKV 64
#define NPAIR 40
__device__ __constant__ uint8_t c_pair[NPAIR] = {
  12,16,20,24,28,29,32,33,36,37,40,41,44,45,46,48,49,50,52,53,54,56,57,58,60,61,62,63, // 8-iter
  8,25,42,59,   // 6-iter
  4,21,38,55,   // 4-iter
  0,17,34,51    // 2-iter
};
__device__ __constant__ uint8_t c_base[16] = {0,1,2,3,4,6,8,10,12,15,18,21,24,28,32,36};

__global__ __launch_bounds__(256) void k_flash_split(
    const uint16_t* __restrict__ Qb, const uint16_t* __restrict__ Kb,
    const uint16_t* __restrict__ VT, uint16_t* __restrict__ Opart,
    float* __restrict__ ml)
{
  const int pair = c_pair[blockIdx.x];
  const int qt   = pair >> 2;
  const int seg  = pair & 3;
  const int h    = blockIdx.y;
  const int kvh  = h >> 2;
  const int slot = h * NPAIR + c_base[qt] + seg;
  const int tid  = threadIdx.x;
  const int lane = tid & 63;
  const int wv   = tid >> 6;
  const int quad = lane >> 4;
  const int l16  = lane & 15;
  const int q0   = qt * 128;

  __shared__ __align__(16) uint16_t sK[BKV * 128];
  __shared__ __align__(16) uint16_t sVT[HD * BKV];
  __shared__ __align__(16) uint16_t sP[4 * 32 * 72];

  const uint16_t* Kbase  = Kb + kvh * HD;
  const uint16_t* VTbase = VT + (size_t)kvh * HD * SEQ;

  bf16x8 qf[2][4];
  #pragma unroll
  for (int mt = 0; mt < 2; mt++)
    #pragma unroll
    for (int ks = 0; ks < 4; ks++)
      qf[mt][ks] = ld_frag(Qb + (size_t)(q0 + wv * 32 + mt * 16 + l16) * DIM + h * HD + ks * 32 + quad * 8);

  __align__(16) uint16_t ones_bits[8];
  #pragma unroll
  for (int j = 0; j < 8; j++) ones_bits[j] = (l16 == 0) ? 0x3F80 : 0;
  const bf16x8 onesf = *(const bf16x8*)ones_bits;

  f32x4 Oacc[2][8] = {};
  f32x4 Lacc[2] = {};

  const float scale = 0.08838834764831845f;  // 1/sqrt(128)
  const float MFIX = 12.0f;
  const int j0 = seg * 8;
  const int j1 = min(j0 + 8, 2 * (qt + 1));

  for (int j = j0; j < j1; j++) {
    const int t0 = j * BKV;
    #pragma unroll
    for (int i = 0; i < 4; i++) {
      int pos = i * 256 + tid;
      int row = pos >> 4, g = (pos & 15) ^ (row & 7);
      async_cp16(Kbase + (size_t)(t0 + row) * KVDIM + g * 8, sK + pos * 8);
      int vrow = pos >> 3, vg = (pos & 7) ^ (vrow & 7);
      async_cp16(VTbase + (size_t)vrow * SEQ + t0 + vg * 8, sVT + pos * 8);
    }
    __syncthreads();

    bool active = (t0 <= q0 + wv * 32 + 31);  // wave-uniform
    if (active) {
      f32x4 Sacc[2][4] = {};
      #pragma unroll
      for (int ks = 0; ks < 4; ks++) {
        bf16x8 kf[4];
        #pragma unroll
        for (int nt = 0; nt < 4; nt++)
          kf[nt] = ld_frag(sK + (nt * 16 + l16) * 128 + (((ks * 4 + quad) ^ (l16 & 7)) * 8));
        #pragma unroll
        for (int mt = 0; mt < 2; mt++)
          #pragma unroll
          for (int nt = 0; nt < 4; nt++)
            Sacc[mt][nt] = __builtin_amdgcn_mfma_f32_16x16x32_bf16(qf[mt][ks], kf[nt], Sacc[mt][nt], 0, 0, 0);
      }
      const bool diag = (t0 + BKV - 1) > (q0 + wv * 32);
      #pragma unroll
      for (int mt = 0; mt < 2; mt++)
        #pragma unroll
        for (int nt = 0; nt < 4; nt++)
          #pragma unroll
          for (int r = 0; r < 4; r++) {
            float sv = Sacc[mt][nt][r] * scale - MFIX;
            bool msk = false;
            if (diag) {
              int qg = q0 + wv * 32 + mt * 16 + quad * 4 + r;
              int tg = t0 + nt * 16 + l16;
              msk = tg > qg;
            }
            float pv = msk ? 0.0f : __expf(sv);
            sP[(wv * 32 + mt * 16 + quad * 4 + r) * 72 + nt * 16 + l16] = f2bf(pv);
          }
      #pragma unroll
      for (int ks = 0; ks < 2; ks++) {
        bf16x8 pf[2], vf[8];
        #pragma unroll
        for (int mt = 0; mt < 2; mt++)
          pf[mt] = ld_frag(sP + (wv * 32 + mt * 16 + l16) * 72 + ks * 32 + quad * 8);
        #pragma unroll
        for (int dt = 0; dt < 8; dt++)
          vf[dt] = ld_frag(sVT + (dt * 16 + l16) * 64 + (((ks * 4 + quad) ^ (l16 & 7)) * 8));
        #pragma unroll
        for (int mt = 0; mt < 2; mt++) {
          Lacc[mt] = __builtin_amdgcn_mfma_f32_16x16x32_bf16(pf[mt], onesf, Lacc[mt], 0, 0, 0);
          #pragma unroll
          for (int dt = 0; dt < 8; dt++)
            Oacc[mt][dt] = __builtin_amdgcn_mfma_f32_16x16x32_bf16(pf[mt], vf[dt], Oacc[mt][dt], 0, 0, 0);
        }
      }
    }
    __syncthreads();
  }

  uint16_t* Op = Opart + (size_t)slot * (128 * 128);
  #pragma unroll
  for (int mt = 0; mt < 2; mt++)
    #pragma unroll
    for (int r = 0; r < 4; r++) {
      int row = wv * 32 + mt * 16 + quad * 4 + r;
      #pragma unroll
      for (int dt = 0; dt < 8; dt++)
        Op[row * 128 + dt * 16 + l16] = f2bf(Oacc[mt][dt][r]);
      if (l16 == 0)
        ml[(size_t)slot * 128 + row] = Lacc[mt][r];
    }
}

// ---------------- combine partials -> attn output (bf16) ----------------
__global__ __launch_bounds__(256) void k_combine(
    const uint16_t* __restrict__ Opart, const float* __restrict__ ml,
    uint16_t* __restrict__ attnb)
{
  const int qt = blockIdx.x;
  const int h  = blockIdx.y;
  const int nseg = (qt >> 2) + 1;
  const int slot0 = h * NPAIR + c_base[qt];
  const int tid = threadIdx.x;
  const int row = tid >> 1;
  const int dh  = (tid & 1) * 64;

  float L = 0.0f;
  #pragma unroll
  for (int i = 0; i < 4; i++)
    if (i < nseg) L += ml[(size_t)(slot0 + i) * 128 + row];
  const float invL = 1.0f / L;

  uint16_t* dst = attnb + (size_t)(qt * 128 + row) * DIM + h * HD + dh;
  #pragma unroll
  for (int c = 0; c < 8; c++) {
    int d = dh + c * 8;
    float acc[8] = {};
    #pragma unroll
    for (int i = 0; i < 4; i++) {
      if (i < nseg) {
        bf16x8 v = ld_frag(Opart + (size_t)(slot0 + i) * (128 * 128) + row * 128 + d);
        #pragma unroll
        for (int j = 0; j < 8; j++) acc[j] += (float)v[j];
      }
    }
    uint16_t outv[8];
    #pragma unroll
    for (int j = 0; j < 8; j++) outv[j] = f2bf(acc[j] * invL);
    *(uint4*)(dst + c * 8) = *(const uint4*)outv;
  }
}

// ---------------- launch ----------------
extern "C" void kernel_launch(void* const* d_in, const int* in_sizes, int n_in,
                              void* d_out, int out_size, void* d_ws, size_t ws_size,
                              hipStream_t stream) {
  const float* x  = (const float*)d_in[0];
  const float* wq = (const float*)d_in[1];
  const float* wk = (const float*)d_in[2];
  const float* wv = (const float*)d_in[3];
  const float* wo = (const float*)d_in[4];
  float* out = (float*)d_out;

  uint8_t* ws = (uint8_t*)d_ws;
  uint16_t* xb     = (uint16_t*)(ws + 0);
  uint16_t* wqkvb  = (uint16_t*)(ws + 16777216ull);
  uint16_t* Qb     = (uint16_t*)(ws + 67108864ull);
  uint16_t* Kb     = (uint16_t*)(ws + 83886080ull);
  uint16_t* Vb     = (uint16_t*)(ws + 88080384ull);
  uint16_t* VT     = (uint16_t*)(ws + 16777216ull);
  uint16_t* Opart  = (uint16_t*)(ws + 20971520ull);
  float*    mlbuf  = (float*)   (ws + 62914560ull);
  uint16_t* wob    = (uint16_t*)(ws + 16777216ull);
  uint16_t* attnb  = xb;

  k_conv_all<<<32768, 256, 0, stream>>>(x, wq, wk, wv, xb, wqkvb);
  k_gemm_qkv<<<dim3(24, 8), 512, 0, stream>>>(xb, wqkvb, Qb, Kb, Vb);
  k_vtrans<<<dim3(32, 16), 256, 0, stream>>>(Vb, VT);
  k_flash_split<<<dim3(NPAIR, 32), 256, 0, stream>>>(Qb, Kb, VT, Opart, mlbuf);
  k_combine<<<dim3(16, 32), 256, 0, stream>>>(Opart, mlbuf, attnb);
  k_conv<<<16384, 256, 0, stream>>>(wo, wob, 4194304);
  k_gemm_o<<<dim3(16, 8), 512, 0, stream>>>(attnb, wob, out);
}